// Round 4
// baseline (215.877 us; speedup 1.0000x reference)
//
#include <hip/hip_runtime.h>
#include <math.h>

#define BATCH 16
#define CH 256
#define HW 56
#define NPIX (HW*HW)          // 3136
#define KK 7

// ---------------- Kernel 1: fused dwconv-bn x2 + relu6 gate + pooled block means ----
// Barrier-free main path: direct global reads (plane is L1-resident), no halo LDS.
// Only LDS use: part[196] for the deterministic pool reduction.
__global__ __launch_bounds__(256, 4) void k1_fuse(
    const float* __restrict__ x1,
    const float* __restrict__ dw1w, const float* __restrict__ g1, const float* __restrict__ b1,
    const float* __restrict__ m1, const float* __restrict__ v1,
    const float* __restrict__ dw2w, const float* __restrict__ g2, const float* __restrict__ b2,
    const float* __restrict__ m2, const float* __restrict__ v2,
    float* __restrict__ xf,      // ws: x_fuse [B*C*3136]
    float* __restrict__ pooled)  // ws: [B*C*49]
{
    const int bc = blockIdx.x;        // b*256 + c
    const int c  = bc & 255;
    const int t  = threadIdx.x;

    __shared__ float part[196];

    // uniform per-channel constants (scalar loads)
    float w1[9], w2[9];
    #pragma unroll
    for (int k = 0; k < 9; k++) { w1[k] = dw1w[c*9+k]; w2[k] = dw2w[c*9+k]; }
    const float sc1 = g1[c] * rsqrtf(v1[c] + 1e-5f);
    const float be1 = b1[c] - m1[c] * sc1;
    const float sc2 = g2[c] * rsqrtf(v2[c] + 1e-5f);
    const float be2 = b2[c] - m2[c] * sc2;

    const int ty = t / 14, tx = t - ty * 14;     // 4x4 tile at (4ty, 4tx), t<196
    const float* plane = x1 + (size_t)bc * NPIX;

    float res[4][4];
    if (t < 196) {
        const int oy = 4 * ty;
        float y1a[4][4], y2a[4][4];
        #pragma unroll
        for (int a = 0; a < 4; a++)
            #pragma unroll
            for (int e = 0; e < 4; e++) { y1a[a][e] = 0.f; y2a[a][e] = 0.f; }

        #pragma unroll
        for (int iy = 0; iy < 6; iy++) {         // input rows oy-1 .. oy+4
            const int r   = oy - 1 + iy;
            const bool rok = (r >= 0) && (r < 56);
            const int rc  = rok ? r : 0;
            float rb[12];                         // rb[m] = image col 4tx-4+m
            #pragma unroll
            for (int k = 0; k < 3; k++) {
                const int cx  = tx - 1 + k;
                const bool cv = (cx >= 0) && (cx < 14);
                const int cc2 = cv ? cx : 0;
                const bool ok = rok && cv;
                float4 v = *(const float4*)(plane + rc*56 + 4*cc2);  // always in-bounds
                rb[4*k+0] = ok ? v.x : 0.f;
                rb[4*k+1] = ok ? v.y : 0.f;
                rb[4*k+2] = ok ? v.z : 0.f;
                rb[4*k+3] = ok ? v.w : 0.f;
            }
            #pragma unroll
            for (int tyy = 0; tyy < 4; tyy++) {
                const int ky = iy - tyy;          // tap row, needs 0..2
                if (ky >= 0 && ky < 3) {
                    #pragma unroll
                    for (int e = 0; e < 4; e++)
                        #pragma unroll
                        for (int dj = 0; dj < 3; dj++) {
                            float xv = rb[3 + e + dj];   // image col 4tx+e+dj-1
                            y1a[tyy][e] += xv * w1[ky*3+dj];
                            y2a[tyy][e] += xv * w2[ky*3+dj];
                        }
                }
            }
        }
        float tile_sum = 0.f;
        #pragma unroll
        for (int tyy = 0; tyy < 4; tyy++)
            #pragma unroll
            for (int e = 0; e < 4; e++) {
                float y1 = y1a[tyy][e] * sc1 + be1;
                float y2 = y2a[tyy][e] * sc2 + be2;
                float a = fminf(fmaxf(y1, 0.f), 6.f);
                res[tyy][e] = a * y2;
                tile_sum += res[tyy][e];
            }
        part[t] = tile_sum;   // tile (ty,tx) lies wholly in pool cell (ty>>1, tx>>1)
    }
    // barrier BEFORE global stores -> barrier drains only the part[] LDS write
    __syncthreads();
    if (t < 49) {
        int ph = t / 7, pw = t - ph * 7;
        float s = part[(2*ph  )*14 + 2*pw] + part[(2*ph  )*14 + 2*pw + 1]
                + part[(2*ph+1)*14 + 2*pw] + part[(2*ph+1)*14 + 2*pw + 1];
        pooled[(size_t)bc * 49 + t] = s * (1.f/64.f);
    }
    if (t < 196) {
        float* op = xf + (size_t)bc * NPIX;
        #pragma unroll
        for (int tyy = 0; tyy < 4; tyy++) {
            float4 r4; r4.x=res[tyy][0]; r4.y=res[tyy][1]; r4.z=res[tyy][2]; r4.w=res[tyy][3];
            *(float4*)(op + (4*ty + tyy)*56 + 4*tx) = r4;
        }
    }
}

// ---------------- Kernel 2a: h[b][p][o] = gelu(pw1 . pooled + pb1), p=49 is mean ----
__global__ __launch_bounds__(256) void k2a(
    const float* __restrict__ pooled, const float* __restrict__ pw1,
    const float* __restrict__ pb1, float* __restrict__ h)
{
    const int b  = blockIdx.x;
    const int oc = blockIdx.y;        // output chunk 0..3 (16 o each)
    const int t  = threadIdx.x;
    __shared__ float pl[256*50];      // 50 KB: [c][p], p=49 -> channel mean

    const float* pp = pooled + (size_t)b * 256 * 49;
    for (int idx = t; idx < 256*49; idx += 256) {
        int cc = idx / 49, p = idx - cc * 49;
        pl[cc*50 + p] = pp[idx];
    }
    __syncthreads();
    {   // per-channel mean (mean over 49 uniform block means == plane mean)
        float s = 0.f;
        #pragma unroll
        for (int p = 0; p < 49; p++) s += pl[t*50 + p];
        pl[t*50 + 49] = s * (1.f/49.f);
    }
    __syncthreads();

    for (int idx = t; idx < 16*50; idx += 256) {
        int ol = idx / 50, p = idx - ol * 50;
        int o = oc * 16 + ol;
        const float* wrow = pw1 + o * 256;
        float acc = pb1[o];
        #pragma unroll 8
        for (int cc = 0; cc < 256; cc++) acc += wrow[cc] * pl[cc*50 + p];
        float gv = 0.5f * acc * (1.f + erff(acc * 0.70710678118654752f));
        h[((size_t)b * 50 + p) * 64 + o] = gv;   // transposed layout [B][50][64]
    }
}

// ---------------- Kernel 2b: second proj + softmax over G + dynamic w/b ------------
__global__ __launch_bounds__(256) void k2b(
    const float* __restrict__ h, const float* __restrict__ pw2, const float* __restrict__ pb2,
    const float* __restrict__ weight1, const float* __restrict__ bias1,
    float* __restrict__ w_dyn, float* __restrict__ b_dyn)
{
    const int b   = blockIdx.x;
    const int cch = blockIdx.y;       // 0..15, 16 channels each
    const int t   = threadIdx.x;
    const int c_base = cch * 16;

    __shared__ __attribute__((aligned(16))) float hl[50*64];  // 12.8 KB [p][r]
    __shared__ float sl[64*51];       // 13.1 KB [row][p], row = g*16+cl

    const float* hp = h + (size_t)b * 50 * 64;
    for (int i = t; i < 800; i += 256) ((float4*)hl)[i] = ((const float4*)hp)[i];

    const int row = t & 63;           // fixed per thread
    const int pb  = t >> 6;           // 0..3
    const int g   = row >> 4, cl = row & 15;
    const int o2  = (g << 8) + c_base + cl;

    float wreg[64];
    {
        const float4* w4 = (const float4*)(pw2 + (size_t)o2 * 64);
        #pragma unroll
        for (int r4 = 0; r4 < 16; r4++) {
            float4 v = w4[r4];
            wreg[4*r4] = v.x; wreg[4*r4+1] = v.y; wreg[4*r4+2] = v.z; wreg[4*r4+3] = v.w;
        }
    }
    const float bias2 = pb2[o2];
    __syncthreads();

    for (int p = pb; p < 50; p += 4) {
        const float4* hv = (const float4*)&hl[p*64];
        float acc = bias2;
        #pragma unroll
        for (int r4 = 0; r4 < 16; r4++) {
            float4 v = hv[r4];      // broadcast across wave (same p)
            acc += wreg[4*r4]*v.x + wreg[4*r4+1]*v.y + wreg[4*r4+2]*v.z + wreg[4*r4+3]*v.w;
        }
        sl[row*51 + p] = acc;
    }
    __syncthreads();

    for (int idx = t; idx < 16*50; idx += 256) {
        int cl2 = idx / 50, p = idx - cl2 * 50;
        float s0 = sl[(cl2     )*51 + p];
        float s1 = sl[(16 + cl2)*51 + p];
        float s2 = sl[(32 + cl2)*51 + p];
        float s3 = sl[(48 + cl2)*51 + p];
        float mx = fmaxf(fmaxf(s0, s1), fmaxf(s2, s3));
        float e0 = expf(s0-mx), e1 = expf(s1-mx), e2 = expf(s2-mx), e3 = expf(s3-mx);
        float inv = 1.f / (e0+e1+e2+e3);
        e0 *= inv; e1 *= inv; e2 *= inv; e3 *= inv;
        int cc = c_base + cl2;
        if (p < 49) {
            float wv = e0*weight1[(0*256+cc)*49+p] + e1*weight1[(1*256+cc)*49+p]
                     + e2*weight1[(2*256+cc)*49+p] + e3*weight1[(3*256+cc)*49+p];
            w_dyn[((size_t)b*256 + cc)*49 + p] = wv;
        } else {
            b_dyn[b*256 + cc] = e0*bias1[cc] + e1*bias1[256+cc] + e2*bias1[512+cc] + e3*bias1[768+cc];
        }
    }
}

// ---------------- Kernel 3: per-sample dynamic 7x7 depthwise conv ----
// Reads x_fuse from ws, writes d_out (no in-place hazard). Staging loads issued
// before the LDS memset so they're in flight across the first barrier.
#define S3 68
__global__ __launch_bounds__(256) void k3_dyn(
    const float* __restrict__ xf,
    const float* __restrict__ w_dyn, const float* __restrict__ b_dyn,
    float* __restrict__ out)
{
    const int bc = blockIdx.x;
    const int t  = threadIdx.x;
    __shared__ __attribute__((aligned(16))) float halo[62*S3];  // 16.9 KB

    // issue staging loads first (batched, independent)
    const float4* pl4 = (const float4*)(xf + (size_t)bc * NPIX);
    float4 v[4];
    if (t < 196) {
        #pragma unroll
        for (int q = 0; q < 4; q++) v[q] = pl4[q*196 + t];
    }

    {   // border zero-init (overlaps with loads in flight)
        float4 z = make_float4(0.f, 0.f, 0.f, 0.f);
        float4* h4 = (float4*)halo;
        for (int i = t; i < 62*S3/4; i += 256) h4[i] = z;
    }

    float w[49];
    const float* wp = w_dyn + (size_t)bc * 49;   // block-uniform -> s_loads
    #pragma unroll
    for (int k = 0; k < 49; k++) w[k] = wp[k];
    const float bias = b_dyn[bc];
    __syncthreads();

    if (t < 196) {
        #pragma unroll
        for (int q = 0; q < 4; q++) {
            int p = (q*196 + t) * 4;
            int i = p / 56, j = p - i * 56;
            *(float4*)&halo[(i+3)*S3 + 4 + j] = v[q];
        }
    }
    __syncthreads();

    if (t < 196) {
        const int ty = t / 14, tx = t - ty * 14;
        const int oy = ty * 4, ox = tx * 4;
        float acc[4][4];
        #pragma unroll
        for (int a = 0; a < 4; a++)
            #pragma unroll
            for (int bb = 0; bb < 4; bb++) acc[a][bb] = bias;

        #pragma unroll
        for (int iy = 0; iy < 10; iy++) {
            const float* hr = &halo[(oy+iy)*S3 + ox];  // aligned
            float4 a = *(const float4*)hr;             // 3x ds_read_b128
            float4 b = *(const float4*)(hr + 4);
            float4 c = *(const float4*)(hr + 8);
            float row[12];                             // row[m] = image col ox+m-4
            row[0]=a.x; row[1]=a.y; row[2]=a.z; row[3]=a.w;
            row[4]=b.x; row[5]=b.y; row[6]=b.z; row[7]=b.w;
            row[8]=c.x; row[9]=c.y; row[10]=c.z; row[11]=c.w;
            #pragma unroll
            for (int tyy = 0; tyy < 4; tyy++) {
                const int ky = iy - tyy;
                if (ky >= 0 && ky < 7) {
                    #pragma unroll
                    for (int txx = 0; txx < 4; txx++)
                        #pragma unroll
                        for (int kx = 0; kx < 7; kx++)
                            acc[tyy][txx] += row[1+txx+kx] * w[ky*7+kx];
                }
            }
        }
        float* op = out + (size_t)bc * NPIX;
        #pragma unroll
        for (int tyy = 0; tyy < 4; tyy++) {
            float4 r4; r4.x = acc[tyy][0]; r4.y = acc[tyy][1]; r4.z = acc[tyy][2]; r4.w = acc[tyy][3];
            *(float4*)(op + (oy+tyy)*56 + ox) = r4;
        }
    }
}

extern "C" void kernel_launch(void* const* d_in, const int* in_sizes, int n_in,
                              void* d_out, int out_size, void* d_ws, size_t ws_size,
                              hipStream_t stream) {
    const float* x1    = (const float*)d_in[0];
    const float* dw1w  = (const float*)d_in[1];
    const float* dw1g  = (const float*)d_in[2];
    const float* dw1b  = (const float*)d_in[3];
    const float* dw1m  = (const float*)d_in[4];
    const float* dw1v  = (const float*)d_in[5];
    const float* dw2w  = (const float*)d_in[6];
    const float* dw2g  = (const float*)d_in[7];
    const float* dw2b  = (const float*)d_in[8];
    const float* dw2m  = (const float*)d_in[9];
    const float* dw2v  = (const float*)d_in[10];
    const float* weight1 = (const float*)d_in[11];
    const float* bias1   = (const float*)d_in[12];
    const float* pw1     = (const float*)d_in[13];
    const float* pb1     = (const float*)d_in[14];
    const float* pw2     = (const float*)d_in[15];
    const float* pb2     = (const float*)d_in[16];

    float* out = (float*)d_out;
    float* ws  = (float*)d_ws;
    float* xfuse  = ws;                    // 16*256*3136 = 12,845,056
    float* pooled = ws + 12845056;         // 16*256*49   =    200,704
    float* h      = ws + 13045760;         // 16*50*64    =     51,200
    float* w_dyn  = ws + 13096960;         // 16*256*49   =    200,704
    float* b_dyn  = ws + 13297664;         // 16*256      =      4,096

    k1_fuse<<<BATCH*CH, 256, 0, stream>>>(x1, dw1w, dw1g, dw1b, dw1m, dw1v,
                                          dw2w, dw2g, dw2b, dw2m, dw2v, xfuse, pooled);
    k2a<<<dim3(BATCH, 4), 256, 0, stream>>>(pooled, pw1, pb1, h);
    k2b<<<dim3(BATCH, 16), 256, 0, stream>>>(h, pw2, pb2, weight1, bias1, w_dyn, b_dyn);
    k3_dyn<<<BATCH*CH, 256, 0, stream>>>(xfuse, w_dyn, b_dyn, out);
}

// Round 5
// 202.091 us; speedup vs baseline: 1.0682x; 1.0682x over previous
//
#include <hip/hip_runtime.h>
#include <math.h>

#define BATCH 16
#define CH 256
#define HW 56
#define NPIX (HW*HW)          // 3136

// ---- shared device helper: compute 4x4 tile of x_fuse = relu6(bn1(dw1(x))) * bn2(dw2(x))
// via direct global reads of the (L1/L3-resident) x1 plane. Tile at rows 4ty..4ty+3,
// cols 4tx..4tx+3 (ty,tx in 0..13).
__device__ __forceinline__ void fuse_tile(
    const float* __restrict__ plane, int ty, int tx,
    const float w1[9], const float w2[9],
    float sc1, float be1, float sc2, float be2,
    float res[4][4])
{
    const int oy = 4 * ty;
    float y1a[4][4], y2a[4][4];
    #pragma unroll
    for (int a = 0; a < 4; a++)
        #pragma unroll
        for (int e = 0; e < 4; e++) { y1a[a][e] = 0.f; y2a[a][e] = 0.f; }

    #pragma unroll
    for (int iy = 0; iy < 6; iy++) {         // input rows oy-1 .. oy+4
        const int r    = oy - 1 + iy;
        const bool rok = (r >= 0) && (r < 56);
        const int rc   = rok ? r : 0;
        float rb[12];                         // rb[m] = image col 4tx-4+m
        #pragma unroll
        for (int k = 0; k < 3; k++) {
            const int cx  = tx - 1 + k;
            const bool cv = (cx >= 0) && (cx < 14);
            const int cc2 = cv ? cx : 0;
            const bool ok = rok && cv;
            float4 v = *(const float4*)(plane + rc*56 + 4*cc2);  // always in-bounds
            rb[4*k+0] = ok ? v.x : 0.f;
            rb[4*k+1] = ok ? v.y : 0.f;
            rb[4*k+2] = ok ? v.z : 0.f;
            rb[4*k+3] = ok ? v.w : 0.f;
        }
        #pragma unroll
        for (int tyy = 0; tyy < 4; tyy++) {
            const int ky = iy - tyy;          // tap row, needs 0..2
            if (ky >= 0 && ky < 3) {
                #pragma unroll
                for (int e = 0; e < 4; e++)
                    #pragma unroll
                    for (int dj = 0; dj < 3; dj++) {
                        float xv = rb[3 + e + dj];   // image col 4tx+e+dj-1
                        y1a[tyy][e] += xv * w1[ky*3+dj];
                        y2a[tyy][e] += xv * w2[ky*3+dj];
                    }
            }
        }
    }
    #pragma unroll
    for (int tyy = 0; tyy < 4; tyy++)
        #pragma unroll
        for (int e = 0; e < 4; e++) {
            float y1 = y1a[tyy][e] * sc1 + be1;
            float y2 = y2a[tyy][e] * sc2 + be2;
            float a = fminf(fmaxf(y1, 0.f), 6.f);
            res[tyy][e] = a * y2;
        }
}

// ---------------- Kernel 1: fuse (no store) -> pooled block means only ----
__global__ __launch_bounds__(256) void k1_pool(
    const float* __restrict__ x1,
    const float* __restrict__ dw1w, const float* __restrict__ g1, const float* __restrict__ b1,
    const float* __restrict__ m1, const float* __restrict__ v1,
    const float* __restrict__ dw2w, const float* __restrict__ g2, const float* __restrict__ b2,
    const float* __restrict__ m2, const float* __restrict__ v2,
    float* __restrict__ pooled)  // ws: [B*C*49]
{
    const int bc = blockIdx.x;        // b*256 + c
    const int c  = bc & 255;
    const int t  = threadIdx.x;

    __shared__ float part[196];

    float w1[9], w2[9];
    #pragma unroll
    for (int k = 0; k < 9; k++) { w1[k] = dw1w[c*9+k]; w2[k] = dw2w[c*9+k]; }
    const float sc1 = g1[c] * rsqrtf(v1[c] + 1e-5f);
    const float be1 = b1[c] - m1[c] * sc1;
    const float sc2 = g2[c] * rsqrtf(v2[c] + 1e-5f);
    const float be2 = b2[c] - m2[c] * sc2;

    if (t < 196) {
        const int ty = t / 14, tx = t - ty * 14;
        float res[4][4];
        fuse_tile(x1 + (size_t)bc * NPIX, ty, tx, w1, w2, sc1, be1, sc2, be2, res);
        float s = 0.f;
        #pragma unroll
        for (int a = 0; a < 4; a++)
            #pragma unroll
            for (int e = 0; e < 4; e++) s += res[a][e];
        part[t] = s;   // tile (ty,tx) lies wholly in pool cell (ty>>1, tx>>1)
    }
    __syncthreads();
    if (t < 49) {
        int ph = t / 7, pw = t - ph * 7;
        float s = part[(2*ph  )*14 + 2*pw] + part[(2*ph  )*14 + 2*pw + 1]
                + part[(2*ph+1)*14 + 2*pw] + part[(2*ph+1)*14 + 2*pw + 1];
        pooled[(size_t)bc * 49 + t] = s * (1.f/64.f);
    }
}

// ---------------- Kernel 2a: h[b][p][o] = gelu(pw1 . pooled + pb1), p=49 is mean ----
__global__ __launch_bounds__(256) void k2a(
    const float* __restrict__ pooled, const float* __restrict__ pw1,
    const float* __restrict__ pb1, float* __restrict__ h)
{
    const int b  = blockIdx.x;
    const int oc = blockIdx.y;        // output chunk 0..3 (16 o each)
    const int t  = threadIdx.x;
    __shared__ float pl[256*50];      // 50 KB: [c][p], p=49 -> channel mean

    const float* pp = pooled + (size_t)b * 256 * 49;
    for (int idx = t; idx < 256*49; idx += 256) {
        int cc = idx / 49, p = idx - cc * 49;
        pl[cc*50 + p] = pp[idx];
    }
    __syncthreads();
    {   // per-channel mean (mean over 49 uniform block means == plane mean)
        float s = 0.f;
        #pragma unroll
        for (int p = 0; p < 49; p++) s += pl[t*50 + p];
        pl[t*50 + 49] = s * (1.f/49.f);
    }
    __syncthreads();

    for (int idx = t; idx < 16*50; idx += 256) {
        int ol = idx / 50, p = idx - ol * 50;
        int o = oc * 16 + ol;
        const float* wrow = pw1 + o * 256;
        float acc = pb1[o];
        #pragma unroll 8
        for (int cc = 0; cc < 256; cc++) acc += wrow[cc] * pl[cc*50 + p];
        float gv = 0.5f * acc * (1.f + erff(acc * 0.70710678118654752f));
        h[((size_t)b * 50 + p) * 64 + o] = gv;   // transposed layout [B][50][64]
    }
}

// ---------------- Kernel 2b: second proj + softmax over G + dynamic w/b ------------
__global__ __launch_bounds__(256) void k2b(
    const float* __restrict__ h, const float* __restrict__ pw2, const float* __restrict__ pb2,
    const float* __restrict__ weight1, const float* __restrict__ bias1,
    float* __restrict__ w_dyn, float* __restrict__ b_dyn)
{
    const int b   = blockIdx.x;
    const int cch = blockIdx.y;       // 0..15, 16 channels each
    const int t   = threadIdx.x;
    const int c_base = cch * 16;

    __shared__ __attribute__((aligned(16))) float hl[50*64];  // 12.8 KB [p][r]
    __shared__ float sl[64*51];       // 13.1 KB [row][p], row = g*16+cl

    const float* hp = h + (size_t)b * 50 * 64;
    for (int i = t; i < 800; i += 256) ((float4*)hl)[i] = ((const float4*)hp)[i];

    const int row = t & 63;           // fixed per thread
    const int pb  = t >> 6;           // 0..3
    const int g   = row >> 4, cl = row & 15;
    const int o2  = (g << 8) + c_base + cl;

    float wreg[64];
    {
        const float4* w4 = (const float4*)(pw2 + (size_t)o2 * 64);
        #pragma unroll
        for (int r4 = 0; r4 < 16; r4++) {
            float4 v = w4[r4];
            wreg[4*r4] = v.x; wreg[4*r4+1] = v.y; wreg[4*r4+2] = v.z; wreg[4*r4+3] = v.w;
        }
    }
    const float bias2 = pb2[o2];
    __syncthreads();

    for (int p = pb; p < 50; p += 4) {
        const float4* hv = (const float4*)&hl[p*64];
        float acc = bias2;
        #pragma unroll
        for (int r4 = 0; r4 < 16; r4++) {
            float4 v = hv[r4];      // broadcast across wave (same p)
            acc += wreg[4*r4]*v.x + wreg[4*r4+1]*v.y + wreg[4*r4+2]*v.z + wreg[4*r4+3]*v.w;
        }
        sl[row*51 + p] = acc;
    }
    __syncthreads();

    for (int idx = t; idx < 16*50; idx += 256) {
        int cl2 = idx / 50, p = idx - cl2 * 50;
        float s0 = sl[(cl2     )*51 + p];
        float s1 = sl[(16 + cl2)*51 + p];
        float s2 = sl[(32 + cl2)*51 + p];
        float s3 = sl[(48 + cl2)*51 + p];
        float mx = fmaxf(fmaxf(s0, s1), fmaxf(s2, s3));
        float e0 = expf(s0-mx), e1 = expf(s1-mx), e2 = expf(s2-mx), e3 = expf(s3-mx);
        float inv = 1.f / (e0+e1+e2+e3);
        e0 *= inv; e1 *= inv; e2 *= inv; e3 *= inv;
        int cc = c_base + cl2;
        if (p < 49) {
            float wv = e0*weight1[(0*256+cc)*49+p] + e1*weight1[(1*256+cc)*49+p]
                     + e2*weight1[(2*256+cc)*49+p] + e3*weight1[(3*256+cc)*49+p];
            w_dyn[((size_t)b*256 + cc)*49 + p] = wv;
        } else {
            b_dyn[b*256 + cc] = e0*bias1[cc] + e1*bias1[256+cc] + e2*bias1[512+cc] + e3*bias1[768+cc];
        }
    }
}

// ---------------- Kernel 3: recompute x_fuse into LDS halo, then dynamic 7x7 conv ----
// Phase A: fuse_tile from global x1 (L3-warm) -> LDS halo (62 rows x 68 stride,
// image row i -> LDS row i+3, image col j -> LDS col j+4; borders zero).
// Phase B: 7x7 depthwise conv with block-uniform dynamic weights -> d_out.
#define S3 68
__global__ __launch_bounds__(256) void k3_dyn(
    const float* __restrict__ x1,
    const float* __restrict__ dw1w, const float* __restrict__ g1, const float* __restrict__ b1,
    const float* __restrict__ m1, const float* __restrict__ v1,
    const float* __restrict__ dw2w, const float* __restrict__ g2, const float* __restrict__ b2,
    const float* __restrict__ m2, const float* __restrict__ v2,
    const float* __restrict__ w_dyn, const float* __restrict__ b_dyn,
    float* __restrict__ out)
{
    const int bc = blockIdx.x;
    const int c  = bc & 255;
    const int t  = threadIdx.x;
    __shared__ __attribute__((aligned(16))) float halo[62*S3];  // 16.9 KB

    // block-uniform constants (scalar path)
    float w1[9], w2[9];
    #pragma unroll
    for (int k = 0; k < 9; k++) { w1[k] = dw1w[c*9+k]; w2[k] = dw2w[c*9+k]; }
    const float sc1 = g1[c] * rsqrtf(v1[c] + 1e-5f);
    const float be1 = b1[c] - m1[c] * sc1;
    const float sc2 = g2[c] * rsqrtf(v2[c] + 1e-5f);
    const float be2 = b2[c] - m2[c] * sc2;
    float wk[49];
    const float* wp = w_dyn + (size_t)bc * 49;   // block-uniform -> s_loads
    #pragma unroll
    for (int k = 0; k < 49; k++) wk[k] = wp[k];
    const float bias = b_dyn[bc];

    {   // zero halo (borders must be 0; interior overwritten in phase A)
        float4 z = make_float4(0.f, 0.f, 0.f, 0.f);
        float4* h4 = (float4*)halo;
        for (int i = t; i < 62*S3/4; i += 256) h4[i] = z;
    }
    __syncthreads();

    const int ty = t / 14, tx = t - ty * 14;
    if (t < 196) {
        float res[4][4];
        fuse_tile(x1 + (size_t)bc * NPIX, ty, tx, w1, w2, sc1, be1, sc2, be2, res);
        #pragma unroll
        for (int tyy = 0; tyy < 4; tyy++) {
            float4 r4; r4.x=res[tyy][0]; r4.y=res[tyy][1]; r4.z=res[tyy][2]; r4.w=res[tyy][3];
            *(float4*)&halo[(4*ty + tyy + 3)*S3 + 4 + 4*tx] = r4;
        }
    }
    __syncthreads();

    if (t < 196) {
        const int oy = ty * 4, ox = tx * 4;
        float acc[4][4];
        #pragma unroll
        for (int a = 0; a < 4; a++)
            #pragma unroll
            for (int bb = 0; bb < 4; bb++) acc[a][bb] = bias;

        #pragma unroll
        for (int iy = 0; iy < 10; iy++) {
            const float* hr = &halo[(oy+iy)*S3 + ox];  // aligned
            float4 a = *(const float4*)hr;             // 3x ds_read_b128
            float4 b = *(const float4*)(hr + 4);
            float4 cc = *(const float4*)(hr + 8);
            float row[12];                             // row[m] = image col ox+m-4
            row[0]=a.x; row[1]=a.y; row[2]=a.z; row[3]=a.w;
            row[4]=b.x; row[5]=b.y; row[6]=b.z; row[7]=b.w;
            row[8]=cc.x; row[9]=cc.y; row[10]=cc.z; row[11]=cc.w;
            #pragma unroll
            for (int tyy = 0; tyy < 4; tyy++) {
                const int ky = iy - tyy;
                if (ky >= 0 && ky < 7) {
                    #pragma unroll
                    for (int txx = 0; txx < 4; txx++)
                        #pragma unroll
                        for (int kx = 0; kx < 7; kx++)
                            acc[tyy][txx] += row[1+txx+kx] * wk[ky*7+kx];
                }
            }
        }
        float* op = out + (size_t)bc * NPIX;
        #pragma unroll
        for (int tyy = 0; tyy < 4; tyy++) {
            float4 r4; r4.x = acc[tyy][0]; r4.y = acc[tyy][1]; r4.z = acc[tyy][2]; r4.w = acc[tyy][3];
            *(float4*)(op + (oy+tyy)*56 + ox) = r4;
        }
    }
}

extern "C" void kernel_launch(void* const* d_in, const int* in_sizes, int n_in,
                              void* d_out, int out_size, void* d_ws, size_t ws_size,
                              hipStream_t stream) {
    const float* x1    = (const float*)d_in[0];
    const float* dw1w  = (const float*)d_in[1];
    const float* dw1g  = (const float*)d_in[2];
    const float* dw1b  = (const float*)d_in[3];
    const float* dw1m  = (const float*)d_in[4];
    const float* dw1v  = (const float*)d_in[5];
    const float* dw2w  = (const float*)d_in[6];
    const float* dw2g  = (const float*)d_in[7];
    const float* dw2b  = (const float*)d_in[8];
    const float* dw2m  = (const float*)d_in[9];
    const float* dw2v  = (const float*)d_in[10];
    const float* weight1 = (const float*)d_in[11];
    const float* bias1   = (const float*)d_in[12];
    const float* pw1     = (const float*)d_in[13];
    const float* pb1     = (const float*)d_in[14];
    const float* pw2     = (const float*)d_in[15];
    const float* pb2     = (const float*)d_in[16];

    float* out = (float*)d_out;
    float* ws  = (float*)d_ws;
    float* pooled = ws;                    // 16*256*49 = 200,704
    float* h      = ws + 200704;           // 16*50*64  =  51,200
    float* w_dyn  = ws + 251904;           // 16*256*49 = 200,704
    float* b_dyn  = ws + 452608;           // 16*256    =   4,096

    k1_pool<<<BATCH*CH, 256, 0, stream>>>(x1, dw1w, dw1g, dw1b, dw1m, dw1v,
                                          dw2w, dw2g, dw2b, dw2m, dw2v, pooled);
    k2a<<<dim3(BATCH, 4), 256, 0, stream>>>(pooled, pw1, pb1, h);
    k2b<<<dim3(BATCH, 16), 256, 0, stream>>>(h, pw2, pb2, weight1, bias1, w_dyn, b_dyn);
    k3_dyn<<<BATCH*CH, 256, 0, stream>>>(x1, dw1w, dw1g, dw1b, dw1m, dw1v,
                                         dw2w, dw2g, dw2b, dw2m, dw2v,
                                         w_dyn, b_dyn, out);
}